// Round 16
// baseline (69.901 us; speedup 1.0000x reference)
//
#include <hip/hip_runtime.h>
#include <math.h>

// Problem constants
#define BATCH 4096
#define NFEAT 2048
#define NNEUR 1024
#define NTGT  8
#define NNZ1  65536
#define NNZ2  8192

// out[n][t] = b2[t] + sum_m sigmoid(sum_k W1[m][k]x[n][k] + b1[m]) * W2[m][t]
// BARRIER-FREE GEMM: both operands pre-packed in MFMA-fragment order;
// each wave loads fragments global->registers (no LDS, no s_barrier in the
// K-loop). Wave tile 64x64 (16 MFMA 16x16x32 per step, K-step 32, 64 steps).
// Block = 4 waves sharing one 64-row A panel (identical A loads -> L1).
// Grid 256 = 1 block/CU; XCD map keeps xp slice 2MB (L2-resident).
#define KSTEPS (NFEAT / 32)   // 64

typedef short  bf16x8 __attribute__((ext_vector_type(8)));
typedef float  f32x4  __attribute__((ext_vector_type(4)));

// ---------------- workspace layout (bytes) ----------------
#define OFF_W1F  ((size_t)0)
#define OFF_W2D  ((size_t)8388608)
#define OFF_W1P  ((size_t)8421376)       // fragment-packed W1 (4 MB)
#define OFF_XP   ((size_t)12615680)      // fragment-packed x  (16 MB)

#define ZERO_FLOAT4 526336               // W1f+W2d contiguous
#define OUT_FLOAT4  (BATCH * NTGT / 4)   // 8192

// 8x f32 -> 8x bf16 (RNE) packed in uint4, via v_cvt_pk_bf16_f32
__device__ __forceinline__ uint4 pk8(float4 lo, float4 hi) {
    uint4 r;
    asm("v_cvt_pk_bf16_f32 %0, %1, %2" : "=v"(r.x) : "v"(lo.x), "v"(lo.y));
    asm("v_cvt_pk_bf16_f32 %0, %1, %2" : "=v"(r.y) : "v"(lo.z), "v"(lo.w));
    asm("v_cvt_pk_bf16_f32 %0, %1, %2" : "=v"(r.z) : "v"(hi.x), "v"(hi.y));
    asm("v_cvt_pk_bf16_f32 %0, %1, %2" : "=v"(r.w) : "v"(hi.z), "v"(hi.w));
    return r;
}

// zero W1f+W2d and pre-fill out with b2 (k_gemm atomicAdds into out)
__global__ void k_zero(float4* __restrict__ ws4, float4* __restrict__ out4,
                       const float* __restrict__ b2) {
    int i = blockIdx.x * blockDim.x + threadIdx.x;
    if (i < ZERO_FLOAT4) {
        ws4[i] = make_float4(0.f, 0.f, 0.f, 0.f);
    } else {
        int j = i - ZERO_FLOAT4;
        if (j < OUT_FLOAT4) {
            int p = (j & 1) * 4;
            out4[j] = make_float4(b2[p], b2[p + 1], b2[p + 2], b2[p + 3]);
        }
    }
}

// scatter-add edges into dense W1f and W2d (handles duplicate edges by summing)
__global__ void k_build(const float* __restrict__ w1, const int* __restrict__ c1o,
                        const int* __restrict__ c1i,
                        const float* __restrict__ w2, const int* __restrict__ c2o,
                        const int* __restrict__ c2i,
                        float* __restrict__ W1f, float* __restrict__ W2d) {
    int i = blockIdx.x * blockDim.x + threadIdx.x;
    if (i < NNZ1) {
        atomicAdd(&W1f[(size_t)c1o[i] * NFEAT + c1i[i]], w1[i]);
    } else {
        int j = i - NNZ1;
        if (j < NNZ2) atomicAdd(&W2d[c2i[j] * NTGT + c2o[j]], w2[j]);
    }
}

// pack W1f into per-step MFMA A-fragment order (bf16).
// unit u: lane=u&63, i=(u>>6)&3, T=(u>>8)&63, mp=u>>14
//   row = mp*64 + i*16 + (lane&15), k = T*32 + (lane>>4)*8
// => wave (mp) step T frag i is units [mp*16384 + T*256 + i*64 .. +64) :
//    one fully-coalesced 1KB read.
__global__ void k_pack(const float* __restrict__ W1f, unsigned short* __restrict__ W1p) {
    int u = blockIdx.x * blockDim.x + threadIdx.x;   // 262144 units
    int lane = u & 63;
    int i    = (u >> 6) & 3;
    int T    = (u >> 8) & 63;
    int mp   = u >> 14;
    int row = mp * 64 + i * 16 + (lane & 15);
    int k   = T * 32 + (lane >> 4) * 8;
    const float* src = &W1f[(size_t)row * NFEAT + k];
    float4 lo = *(const float4*)src;
    float4 hi = *(const float4*)(src + 4);
    ((uint4*)W1p)[u] = pk8(lo, hi);
}

// pack x into per-step MFMA B-fragment order (bf16). Same unit decode over N:
// unit u: lane=u&63, j=(u>>6)&3, T=(u>>8)&63, nb=u>>14 (64 n-groups)
//   row(n) = nb*64 + j*16 + (lane&15), k = T*32 + (lane>>4)*8
__global__ void k_packx(const float* __restrict__ x, unsigned short* __restrict__ xp) {
    int u = blockIdx.x * blockDim.x + threadIdx.x;   // 1048576 units
    int lane = u & 63;
    int j    = (u >> 6) & 3;
    int T    = (u >> 8) & 63;
    int nb   = u >> 14;
    int row = nb * 64 + j * 16 + (lane & 15);
    int k   = T * 32 + (lane >> 4) * 8;
    const float* src = &x[(size_t)row * NFEAT + k];
    float4 lo = *(const float4*)src;
    float4 hi = *(const float4*)(src + 4);
    ((uint4*)xp)[u] = pk8(lo, hi);
}

// Barrier-free bf16 MFMA GEMM + fused bias/sigmoid/layer-2 epilogue.
__global__ __launch_bounds__(256) void k_gemm(const unsigned short* __restrict__ W1p,
                                              const unsigned short* __restrict__ xp,
                                              const float* __restrict__ b1,
                                              const float* __restrict__ W2d,
                                              float* __restrict__ out) {
    // XCD map: xcd = bid&7 owns 2 n-quarters (xp slice 2 MB, L2-resident)
    // x all 16 m-panels. Bijective over 256 blocks.
    int bid = blockIdx.x;
    int xcd = bid & 7;
    int i5  = bid >> 3;                    // 0..31
    int nq  = xcd * 2 + (i5 & 1);          // 0..15 (256-col group)
    int mp  = i5 >> 1;                     // 0..15 (64-row A panel)

    int tid  = threadIdx.x;
    int wv   = tid >> 6;
    int lane = tid & 63;
    int nb   = nq * 4 + wv;                // wave's 64-col n-group
    int lr = lane & 15, lg = lane >> 4;

    const bf16x8* gA = (const bf16x8*)W1p + (size_t)mp * 16384 + lane;
    const bf16x8* gB = (const bf16x8*)xp  + (size_t)nb * 16384 + lane;

    f32x4 acc[4][4];
#pragma unroll
    for (int i = 0; i < 4; ++i)
#pragma unroll
        for (int j = 0; j < 4; ++j) acc[i][j] = (f32x4){0.f, 0.f, 0.f, 0.f};

    // two named register sets; no LDS, no barriers — compiler pipelines with
    // precisely-counted vmcnt (loads for T+2 issue right after MFMAs of T).
    bf16x8 A0[4], B0[4], A1[4], B1[4];

#define LOADS0(T) do {                                              \
        _Pragma("unroll")                                           \
        for (int c = 0; c < 4; ++c) {                               \
            A0[c] = gA[(T) * 256 + c * 64];                         \
            B0[c] = gB[(T) * 256 + c * 64];                         \
        } } while (0)
#define LOADS1(T) do {                                              \
        _Pragma("unroll")                                           \
        for (int c = 0; c < 4; ++c) {                               \
            A1[c] = gA[(T) * 256 + c * 64];                         \
            B1[c] = gB[(T) * 256 + c * 64];                         \
        } } while (0)
#define MFMAS0() do {                                               \
        _Pragma("unroll")                                           \
        for (int i = 0; i < 4; ++i)                                 \
            _Pragma("unroll")                                       \
            for (int j = 0; j < 4; ++j)                             \
                acc[i][j] = __builtin_amdgcn_mfma_f32_16x16x32_bf16(A0[i], B0[j], acc[i][j], 0, 0, 0); \
    } while (0)
#define MFMAS1() do {                                               \
        _Pragma("unroll")                                           \
        for (int i = 0; i < 4; ++i)                                 \
            _Pragma("unroll")                                       \
            for (int j = 0; j < 4; ++j)                             \
                acc[i][j] = __builtin_amdgcn_mfma_f32_16x16x32_bf16(A1[i], B1[j], acc[i][j], 0, 0, 0); \
    } while (0)

    LOADS0(0);
    LOADS1(1);
    // steady state: 31 pairs, tiles 0..61; loads run 2 steps ahead.
#pragma unroll 1
    for (int p = 0; p < 31; ++p) {
        MFMAS0();
        LOADS0(2 * p + 2);
        MFMAS1();
        LOADS1(2 * p + 3);
    }
    MFMAS0();   // tile 62
    MFMAS1();   // tile 63

#undef LOADS0
#undef LOADS1
#undef MFMAS0
#undef MFMAS1

    // ---- fused epilogue (per wave, no cross-wave comms needed) ----
    // C/D layout: col(n) = lane&15, row(m) = (lane>>4)*4 + reg  [m89-verified]
    // lane's n values: n = nb*64 + j*16 + lr; m values: mp*64 + i*16 + lg*4 + r
    float pt[4][NTGT];
#pragma unroll
    for (int j = 0; j < 4; ++j)
#pragma unroll
        for (int t = 0; t < NTGT; ++t) pt[j][t] = 0.f;

#pragma unroll
    for (int i = 0; i < 4; ++i) {
#pragma unroll
        for (int r = 0; r < 4; ++r) {
            int m = mp * 64 + i * 16 + lg * 4 + r;
            float bn = b1[m];
            float4 w2lo = *(const float4*)&W2d[m * NTGT];
            float4 w2hi = *(const float4*)&W2d[m * NTGT + 4];
#pragma unroll
            for (int j = 0; j < 4; ++j) {
                float h = 1.f / (1.f + __expf(-(acc[i][j][r] + bn)));
                pt[j][0] += h * w2lo.x; pt[j][1] += h * w2lo.y;
                pt[j][2] += h * w2lo.z; pt[j][3] += h * w2lo.w;
                pt[j][4] += h * w2hi.x; pt[j][5] += h * w2hi.y;
                pt[j][6] += h * w2hi.z; pt[j][7] += h * w2hi.w;
            }
        }
    }
    // reduce over lg (lanes lr+16*lg share the same n column)
#pragma unroll
    for (int j = 0; j < 4; ++j)
#pragma unroll
        for (int t = 0; t < NTGT; ++t) {
            float val = pt[j][t];
            val += __shfl_xor(val, 16, 64);
            val += __shfl_xor(val, 32, 64);
            pt[j][t] = val;
        }
    if (lg == 0) {
#pragma unroll
        for (int j = 0; j < 4; ++j) {
            int n = nb * 64 + j * 16 + lr;
#pragma unroll
            for (int t = 0; t < NTGT; ++t)
                atomicAdd(&out[(size_t)n * NTGT + t], pt[j][t]);
        }
    }
}

extern "C" void kernel_launch(void* const* d_in, const int* in_sizes, int n_in,
                              void* d_out, int out_size, void* d_ws, size_t ws_size,
                              hipStream_t stream) {
    (void)in_sizes; (void)n_in; (void)out_size; (void)ws_size;
    const float* x   = (const float*)d_in[0];
    const float* w1  = (const float*)d_in[1];
    const float* b1  = (const float*)d_in[2];
    const float* w2  = (const float*)d_in[3];
    const float* b2  = (const float*)d_in[4];
    const int*   c1o = (const int*)d_in[5];
    const int*   c1i = (const int*)d_in[6];
    const int*   c2o = (const int*)d_in[7];
    const int*   c2i = (const int*)d_in[8];
    float* out = (float*)d_out;

    char* ws = (char*)d_ws;
    float*          W1f  = (float*)(ws + OFF_W1F);
    float*          W2d  = (float*)(ws + OFF_W2D);
    unsigned short* W1p  = (unsigned short*)(ws + OFF_W1P);
    unsigned short* xp   = (unsigned short*)(ws + OFF_XP);

    // zero W1f+W2d, pre-fill out with b2
    k_zero<<<(ZERO_FLOAT4 + OUT_FLOAT4 + 255) / 256, 256, 0, stream>>>(
        (float4*)ws, (float4*)out, b2);

    // dense weight build
    k_build<<<(NNZ1 + NNZ2) / 256, 256, 0, stream>>>(w1, c1o, c1i, w2, c2o, c2i, W1f, W2d);

    // pack W1 and x into MFMA-fragment order (bf16)
    k_pack<<<NNEUR * NFEAT / 8 / 256, 256, 0, stream>>>(W1f, W1p);
    k_packx<<<BATCH * NFEAT / 8 / 256, 256, 0, stream>>>(x, xp);

    // barrier-free GEMM + bias + sigmoid + layer-2 (atomic) all fused
    k_gemm<<<256, 256, 0, stream>>>(W1p, xp, b1, W2d, out);
}